// Round 1
// baseline (126.606 us; speedup 1.0000x reference)
//
#include <hip/hip_runtime.h>

// Local 8x8 window autocorrelation, stride 4.
// x: (B, C, H, W) fp32 -> out: (B, C, nH, nW, KH, KW) fp32
// out[n, dy, dx] = sum_{i,j} p[i+dy-4][j+dx-4] * p[i][j]  (zero outside window)

constexpr int KH = 8, KW = 8, SH = 4, SW = 4;
constexpr int B = 8, C = 64, H = 96, W = 96;
constexpr int nH = (H - KH) / SH + 1;  // 23
constexpr int nW = (W - KW) / SW + 1;  // 23
constexpr int NWIN = B * C * nH * nW;  // 270848

__global__ __launch_bounds__(256) void
local_autocorr_kernel(const float* __restrict__ x, float* __restrict__ out) {
    const int n = blockIdx.x * 256 + threadIdx.x;
    if (n >= NWIN) return;

    const int w  = n % nW;
    const int t  = n / nW;
    const int h  = t % nH;
    const int bc = t / nH;  // b*C + c

    const float* xp = x + ((size_t)bc * H + (size_t)h * SH) * W + (size_t)w * SW;

    // Load the 8x8 patch into registers (static indexing only).
    float p[64];
#pragma unroll
    for (int r = 0; r < 8; ++r) {
        const float4 lo = *reinterpret_cast<const float4*>(xp + (size_t)r * W);
        const float4 hi = *reinterpret_cast<const float4*>(xp + (size_t)r * W + 4);
        p[r * 8 + 0] = lo.x; p[r * 8 + 1] = lo.y;
        p[r * 8 + 2] = lo.z; p[r * 8 + 3] = lo.w;
        p[r * 8 + 4] = hi.x; p[r * 8 + 5] = hi.y;
        p[r * 8 + 6] = hi.z; p[r * 8 + 7] = hi.w;
    }

    float* op = out + (size_t)n * 64;

#pragma unroll
    for (int dy = 0; dy < 8; ++dy) {
        const int oy = dy - 4;  // compile-time after unroll
        float accs[8];
#pragma unroll
        for (int dx = 0; dx < 8; ++dx) {
            const int ox = dx - 4;
            float acc = 0.0f;
#pragma unroll
            for (int i = 0; i < 8; ++i) {
                if (i + oy < 0 || i + oy >= 8) continue;  // compile-time DCE
#pragma unroll
                for (int j = 0; j < 8; ++j) {
                    if (j + ox < 0 || j + ox >= 8) continue;
                    acc = fmaf(p[(i + oy) * 8 + (j + ox)], p[i * 8 + j], acc);
                }
            }
            accs[dx] = acc;
        }
        const float4 v0 = make_float4(accs[0], accs[1], accs[2], accs[3]);
        const float4 v1 = make_float4(accs[4], accs[5], accs[6], accs[7]);
        *reinterpret_cast<float4*>(op + dy * 8)     = v0;
        *reinterpret_cast<float4*>(op + dy * 8 + 4) = v1;
    }
}

extern "C" void kernel_launch(void* const* d_in, const int* in_sizes, int n_in,
                              void* d_out, int out_size, void* d_ws, size_t ws_size,
                              hipStream_t stream) {
    const float* x = (const float*)d_in[0];
    float* out = (float*)d_out;

    const int threads = 256;
    const int blocks = (NWIN + threads - 1) / threads;
    local_autocorr_kernel<<<blocks, threads, 0, stream>>>(x, out);
}

// Round 2
// 125.850 us; speedup vs baseline: 1.0060x; 1.0060x over previous
//
#include <hip/hip_runtime.h>

// Local 8x8 window autocorrelation, stride 4.
// x: (B, C, H, W) fp32 -> out: (B, C, nH, nW, KH, KW) fp32
// out[n, dy, dx] = sum_{i,j} p[i+dy-4][j+dx-4] * p[i][j]  (zero outside window)
//
// Parallelization: 16 lanes per window. Lane sub = t%16 computes dy = sub>>1,
// dx in [(sub&1)*4, (sub&1)*4+4). Each lane's 4 outputs are one float4 at
// out + n*64 + sub*4 -> a wave's store is 1 KB fully contiguous (coalesced,
// full-line writebacks; fixes R1's 4.5x write amplification).
// The (oy, ox) shift is folded into the global load ADDRESS so all register
// indexing stays compile-time static (no scratch).

constexpr int KH = 8, KW = 8, SH = 4, SW = 4;
constexpr int B = 8, C = 64, H = 96, W = 96;
constexpr int nH = (H - KH) / SH + 1;  // 23
constexpr int nW = (W - KW) / SW + 1;  // 23
constexpr int NWIN = B * C * nH * nW;  // 270848
constexpr int NTHREADS = NWIN * 16;    // 4333568 = 16928 * 256

__global__ __launch_bounds__(256) void
local_autocorr_kernel(const float* __restrict__ x, float* __restrict__ out) {
    const int t = blockIdx.x * 256 + threadIdx.x;

    const int n   = t >> 4;         // window index
    const int sub = t & 15;         // 0..15 within window
    const int dy  = sub >> 1;       // 0..7
    const int oy  = dy - 4;         // -4..3
    const bool hiHalf = (sub & 1);  // ox0 = 0 if hiHalf else -4

    const int w  = n % nW;
    const int tt = n / nW;
    const int h  = tt % nH;
    const int bc = tt / nH;         // b*C + c

    const float* xp = x + ((size_t)bc * H + (size_t)h * SH) * W + (size_t)w * SW;

    float acc0 = 0.f, acc1 = 0.f, acc2 = 0.f, acc3 = 0.f;

#pragma unroll
    for (int i = 0; i < 8; ++i) {
        // B row i (always in range)
        const float4 blo = *reinterpret_cast<const float4*>(xp + (size_t)i * W);
        const float4 bhi = *reinterpret_cast<const float4*>(xp + (size_t)i * W + 4);
        const float b[8] = {blo.x, blo.y, blo.z, blo.w, bhi.x, bhi.y, bhi.z, bhi.w};

        // A row: zero-padded 12-wide; a[s] = P(i+oy, s + ox0)
        float a[12];
#pragma unroll
        for (int s = 0; s < 12; ++s) a[s] = 0.0f;

        const int ya = i + oy;
        if ((unsigned)ya < 8u) {
            const float4 alo = *reinterpret_cast<const float4*>(xp + (size_t)ya * W);
            const float4 ahi = *reinterpret_cast<const float4*>(xp + (size_t)ya * W + 4);
            if (hiHalf) {
                // ox0 = 0: a[0..7] = row[0..7]
                a[0] = alo.x; a[1] = alo.y; a[2]  = alo.z; a[3]  = alo.w;
                a[4] = ahi.x; a[5] = ahi.y; a[6]  = ahi.z; a[7]  = ahi.w;
            } else {
                // ox0 = -4: a[4..11] = row[0..7]
                a[4] = alo.x; a[5] = alo.y; a[6]  = alo.z; a[7]  = alo.w;
                a[8] = ahi.x; a[9] = ahi.y; a[10] = ahi.z; a[11] = ahi.w;
            }
        }

#pragma unroll
        for (int j = 0; j < 8; ++j) {
            acc0 = fmaf(a[j + 0], b[j], acc0);
            acc1 = fmaf(a[j + 1], b[j], acc1);
            acc2 = fmaf(a[j + 2], b[j], acc2);
            acc3 = fmaf(a[j + 3], b[j], acc3);
        }
    }

    *reinterpret_cast<float4*>(out + (size_t)n * 64 + sub * 4) =
        make_float4(acc0, acc1, acc2, acc3);
}

extern "C" void kernel_launch(void* const* d_in, const int* in_sizes, int n_in,
                              void* d_out, int out_size, void* d_ws, size_t ws_size,
                              hipStream_t stream) {
    const float* x = (const float*)d_in[0];
    float* out = (float*)d_out;

    const int threads = 256;
    const int blocks = NTHREADS / threads;  // 16928, exact
    local_autocorr_kernel<<<blocks, threads, 0, stream>>>(x, out);
}